// Round 1
// 240.137 us; speedup vs baseline: 1.0604x; 1.0604x over previous
//
#include <hip/hip_runtime.h>
#include <stdint.h>

typedef unsigned short u16;
typedef __bf16 bf16x8 __attribute__((ext_vector_type(8)));
typedef float f32x4 __attribute__((ext_vector_type(4)));

__device__ __forceinline__ u16 f2bf(float f) {
  union { float f; uint32_t u; } x; x.f = f;
  uint32_t u = x.u;
  u += 0x7fffu + ((u >> 16) & 1u);   // round-to-nearest-even
  return (u16)(u >> 16);
}
__device__ __forceinline__ float bf2f(uint32_t lo16) {
  union { uint32_t u; float f; } x; x.u = lo16 << 16; return x.f;
}

__device__ __forceinline__ void async_load16(const u16* g, u16* l) {
  __builtin_amdgcn_global_load_lds(
      (const __attribute__((address_space(1))) void*)g,
      (__attribute__((address_space(3))) void*)l,
      16, 0, 0);
}

// ---------------- prep_all: sigmoid(beta) + weight converts + x convert ----------------
__global__ __launch_bounds__(256) void prep_all(const float* __restrict__ x,
                                                const float* __restrict__ Wq,
                                                const float* __restrict__ Wfc,
                                                const float* __restrict__ braw,
                                                u16* __restrict__ xb,
                                                u16* __restrict__ wqb,
                                                u16* __restrict__ wfcb,
                                                float* __restrict__ beta) {
  int gid = blockIdx.x * 256 + threadIdx.x;
  if (gid < 1024) beta[gid] = 1.0f / (1.0f + expf(-braw[gid]));
  if (gid < 131072) {
    const int HH = 1024 * 1024;
    int i = gid * 16;
    const float* src = (i < HH) ? (Wq + i) : (Wfc + (i - HH));
    u16* dst = (i < HH) ? (wqb + i) : (wfcb + (i - HH));
#pragma unroll
    for (int c = 0; c < 4; c++) {
      float4 v = *(const float4*)(src + c * 4);
      ushort4 o = {f2bf(v.x), f2bf(v.y), f2bf(v.z), f2bf(v.w)};
      *(ushort4*)(dst + c * 4) = o;
    }
  }
  {
    int i = gid * 8;
    float4 a = *(const float4*)(x + i);
    float4 b = *(const float4*)(x + i + 4);
    ushort4 o0 = {f2bf(a.x), f2bf(a.y), f2bf(a.z), f2bf(a.w)};
    ushort4 o1 = {f2bf(b.x), f2bf(b.y), f2bf(b.z), f2bf(b.w)};
    *(ushort4*)(xb + i) = o0;
    *(ushort4*)(xb + i + 4) = o1;
  }
}

// ---------------- GEMM: C = A (MxK bf16) * B^T (NxK bf16) + bias ----------------
// 256x256 tile, BK=32, 8 waves (2Mx4N), per-wave 128x64 via 8x4 mfma_f32_16x16x32_bf16.
// T3+T4 deep pipeline: 4-deep LDS K-tile ring (4 x (16KB A + 16KB B) = 128 KiB);
// while computing kt we stage kt+3, and the end-of-iteration wait is a COUNTED
// s_waitcnt vmcnt(8) (2 future tiles x 4 issues in flight) -- never a full drain
// in the main loop (the m97-structure drain stall was the ~25% MfmaUtil ceiling).
// Race-freedom: slot (kt+3)&3 was last ds_read at iteration kt-1; those reads
// complete before that iteration's MFMAs (compiler lgkmcnt), hence before its
// end barrier -- so the async LDS writes for kt+3 can land at any time after.
// The per-wave vmcnt guarantees only its OWN loads; the barrier after it makes
// the guarantee block-wide (each wave stages the rows its own lanes read plus
// rows read by others, so the barrier is contractual, not optional).
// LDS swizzle: chunk ^= (row>>1)&3 (involution), applied by pre-swizzling the
// GLOBAL source (global_load_lds dest must be wave-uniform base + lane*16,
// i.e. linear) and XOR-ing the ds_read chunk. Wave read set = uniform
// permutation of a contiguous 1KB region -> conflict-free (same family as the
// previous kernel's XOR-8, which measured SQ_LDS_BANK_CONFLICT = 0).
template <int RELU, int OUTBF>
__global__ __launch_bounds__(512, 2) void gemm256(const u16* __restrict__ A,
                                                  const u16* __restrict__ B,
                                                  const float* __restrict__ bias,
                                                  void* __restrict__ Cout,
                                                  int M, int N, int K) {
  // ring[slot][matrix][256 rows][32 cols bf16] ; 4*2*16KB = 128 KiB
  __shared__ u16 lds[4][2][256 * 32];

  const int tid  = threadIdx.x;
  const int lane = tid & 63;
  const int wid  = tid >> 6;          // 0..7
  const int wr   = (wid >> 2) * 128;  // wave row offset within tile
  const int wc   = (wid & 3) * 64;    // wave col offset within tile

  const int bid    = blockIdx.x;      // grid = (M/256)*(N/256) = 64*4 = 256 = 1/CU
  const int tile_m = (bid >> 2) * 256;
  const int tile_n = (bid & 3) * 256;

  // staging map: per issue, 512 threads cover 128 rows x 4 chunks(16B).
  // dest is linear (row*64B + chunk*16B); source chunk pre-swizzled.
  const int srow    = tid >> 2;                    // 0..127
  const int schunk  = (tid & 3) ^ ((srow >> 1) & 3);
  const u16* gA = A + (size_t)(tile_m + srow) * K + schunk * 8;
  const u16* gB = B + (size_t)(tile_n + srow) * K + schunk * 8;
  const size_t half_stride = (size_t)128 * K;      // rows 128..255 of the tile

#define STAGE(slot, kt)                                                   \
  do {                                                                    \
    const size_t k0 = (size_t)(kt) * 32;                                  \
    async_load16(gA + k0,               &lds[slot][0][wid * 512]);        \
    async_load16(gA + k0 + half_stride, &lds[slot][0][4096 + wid * 512]); \
    async_load16(gB + k0,               &lds[slot][1][wid * 512]);        \
    async_load16(gB + k0 + half_stride, &lds[slot][1][4096 + wid * 512]); \
  } while (0)

  f32x4 acc[8][4];
#pragma unroll
  for (int i = 0; i < 8; i++)
#pragma unroll
    for (int j = 0; j < 4; j++) acc[i][j] = (f32x4){0.f, 0.f, 0.f, 0.f};

  const int lrow = lane & 15;
  const int kq   = lane >> 4;
  const int kc   = (lrow >> 1) & 3;        // read-side swizzle key
  const int coff = ((kq ^ kc) << 3);       // elem offset within a 32-elem row

  const int NKT = K >> 5;                  // K-tiles of 32 (K=1024 -> 32)

  // prologue: fill 3 ring slots, then wait for slot 0 only (8 newer issues allowed)
  STAGE(0, 0);
  if (NKT > 1) STAGE(1, 1);
  if (NKT > 2) STAGE(2, 2);
  if (NKT > 2)      asm volatile("s_waitcnt vmcnt(8)" ::: "memory");
  else if (NKT > 1) asm volatile("s_waitcnt vmcnt(4)" ::: "memory");
  else              asm volatile("s_waitcnt vmcnt(0)" ::: "memory");
  __builtin_amdgcn_s_barrier();

  for (int kt = 0; kt < NKT; ++kt) {
    const int slot = kt & 3;
    const u16* As = &lds[slot][0][0];
    const u16* Bs = &lds[slot][1][0];

    bf16x8 a[8], b[4];
#pragma unroll
    for (int i = 0; i < 8; i++)
      a[i] = *(const bf16x8*)&As[(wr + i * 16 + lrow) * 32 + coff];
#pragma unroll
    for (int j = 0; j < 4; j++)
      b[j] = *(const bf16x8*)&Bs[(wc + j * 16 + lrow) * 32 + coff];

    if (kt + 3 < NKT) STAGE((kt + 3) & 3, kt + 3);

    __builtin_amdgcn_s_setprio(1);
#pragma unroll
    for (int i = 0; i < 8; i++)
#pragma unroll
      for (int j = 0; j < 4; j++)
        acc[i][j] = __builtin_amdgcn_mfma_f32_16x16x32_bf16(a[i], b[j], acc[i][j], 0, 0, 0);
    __builtin_amdgcn_s_setprio(0);

    // counted wait: guarantee kt+1's 4 issues landed; leave newer tiles in flight.
    const int ahead = NKT - 1 - kt;
    if (ahead >= 3) {
      asm volatile("s_waitcnt vmcnt(8)" ::: "memory");
      __builtin_amdgcn_s_barrier();
    } else if (ahead == 2) {
      asm volatile("s_waitcnt vmcnt(4)" ::: "memory");
      __builtin_amdgcn_s_barrier();
    } else if (ahead == 1) {
      asm volatile("s_waitcnt vmcnt(0)" ::: "memory");
      __builtin_amdgcn_s_barrier();
    }
  }
#undef STAGE

  // C/D layout: col = lane&15, row = (lane>>4)*4 + r  [measured m89/m91]
  const int crow = (lane >> 4) << 2;
  const int ccol = lane & 15;
#pragma unroll
  for (int i = 0; i < 8; i++) {
#pragma unroll
    for (int j = 0; j < 4; j++) {
      const int gm = tile_m + wr + i * 16 + crow;
      const int gn = tile_n + wc + j * 16 + ccol;
      const float bv = bias[gn];
#pragma unroll
      for (int r = 0; r < 4; r++) {
        float v = acc[i][j][r] + bv;
        if (RELU) v = fmaxf(v, 0.f);
        if (OUTBF) ((u16*)Cout)[(size_t)(gm + r) * N + gn] = f2bf(v);
        else       ((float*)Cout)[(size_t)(gm + r) * N + gn] = v;
      }
    }
  }
}

// ---------------- scan: m_t = beta*m_{t-1} + q_t over T=2048, channels = B*H = 8192 ----
// q is bf16 [T][8192]. 64 segments of 32 t-steps.
#define NCH 8192
#define SEG 32
#define NSEG 64

// pass1: per-segment carries (fp32 Horner over bf16 q; no double quantization).
__global__ __launch_bounds__(256) void scan_carry(const uint2* __restrict__ qb,
                                                  float* __restrict__ carry,
                                                  const float* __restrict__ beta_arr) {
  int tid = blockIdx.x * 256 + threadIdx.x;  // [0, 64*2048)
  int seg = tid >> 11;
  int cq  = tid & 2047;                      // channel quad
  int h0  = (cq * 4) & 1023;
  float b0 = beta_arr[h0], b1 = beta_arr[h0 + 1], b2 = beta_arr[h0 + 2], b3 = beta_arr[h0 + 3];
  const uint2* p = qb + (size_t)seg * SEG * 2048 + cq;
  float m0 = 0.f, m1 = 0.f, m2 = 0.f, m3 = 0.f;
#pragma unroll 8
  for (int t = 0; t < SEG; t++) {
    uint2 v = p[(size_t)t * 2048];
    m0 = fmaf(b0, m0, bf2f(v.x & 0xffffu));
    m1 = fmaf(b1, m1, bf2f(v.x >> 16));
    m2 = fmaf(b2, m2, bf2f(v.y & 0xffffu));
    m3 = fmaf(b3, m3, bf2f(v.y >> 16));
  }
  *(float4*)&carry[(size_t)seg * NCH + cq * 4] = make_float4(m0, m1, m2, m3);
}

// pass2 (fused fold + rescan): F = Horner-fold of the seg upstream carries with
// ratio beta^32 (2 MB buffer, L2-resident), then rescan 32 q steps from m=F and
// emit bf16 m. seg is uniform per block (8 blocks per segment).
__global__ __launch_bounds__(256) void scan_fuse(const uint2* __restrict__ qb,
                                                 const float4* __restrict__ carry4,
                                                 const float* __restrict__ beta_arr,
                                                 uint2* __restrict__ mb) {
  const int tid = blockIdx.x * 256 + threadIdx.x;  // [0, 64*2048)
  const int seg = tid >> 11;
  const int cq  = tid & 2047;
  const int h0  = (cq * 4) & 1023;
  const float b0 = beta_arr[h0], b1 = beta_arr[h0 + 1];
  const float b2 = beta_arr[h0 + 2], b3 = beta_arr[h0 + 3];
  float s0 = b0, s1 = b1, s2 = b2, s3 = b3;
#pragma unroll
  for (int i = 0; i < 5; i++) { s0 *= s0; s1 *= s1; s2 *= s2; s3 *= s3; }  // beta^32
  float m0 = 0.f, m1 = 0.f, m2 = 0.f, m3 = 0.f;
  const float4* cp = carry4 + cq;
  for (int s = 0; s < seg; s++) {  // uniform per block
    float4 c = cp[(size_t)s * 2048];
    m0 = fmaf(s0, m0, c.x); m1 = fmaf(s1, m1, c.y);
    m2 = fmaf(s2, m2, c.z); m3 = fmaf(s3, m3, c.w);
  }
  const uint2* p = qb + (size_t)seg * SEG * 2048 + cq;
  uint2* o = mb + (size_t)seg * SEG * 2048 + cq;
#pragma unroll 8
  for (int t = 0; t < SEG; t++) {
    uint2 v = p[(size_t)t * 2048];
    m0 = fmaf(b0, m0, bf2f(v.x & 0xffffu));
    m1 = fmaf(b1, m1, bf2f(v.x >> 16));
    m2 = fmaf(b2, m2, bf2f(v.y & 0xffffu));
    m3 = fmaf(b3, m3, bf2f(v.y >> 16));
    uint2 w;
    w.x = (uint32_t)f2bf(m0) | ((uint32_t)f2bf(m1) << 16);
    w.y = (uint32_t)f2bf(m2) | ((uint32_t)f2bf(m3) << 16);
    o[(size_t)t * 2048] = w;
  }
}

extern "C" void kernel_launch(void* const* d_in, const int* in_sizes, int n_in,
                              void* d_out, int out_size, void* d_ws, size_t ws_size,
                              hipStream_t stream) {
  const float* x        = (const float*)d_in[0];
  const float* W_q      = (const float*)d_in[1];
  const float* b_q      = (const float*)d_in[2];
  const float* beta_raw = (const float*)d_in[3];
  const float* W_fc     = (const float*)d_in[4];
  const float* b_fc     = (const float*)d_in[5];

  const int H = 1024;
  const int M = 2048 * 8;              // T*B = 16384 rows
  const size_t MH = (size_t)M * H;     // 16.7M elements

  char* ws = (char*)d_ws;
  u16* x_bf    = (u16*)ws;  ws += MH * 2;                   // 32 MB
  u16* q_bf    = (u16*)ws;  ws += MH * 2;                   // 32 MB
  u16* m_bf    = (u16*)ws;  ws += MH * 2;                   // 32 MB
  u16* wq_bf   = (u16*)ws;  ws += (size_t)H * H * 2;        // 2 MB
  u16* wfc_bf  = (u16*)ws;  ws += (size_t)H * H * 2;        // 2 MB
  float* beta  = (float*)ws; ws += 4096;
  float* carry = (float*)ws; ws += (size_t)NSEG * NCH * 4;  // 2 MB

  prep_all<<<(int)(MH / 8 / 256), 256, 0, stream>>>(x, W_q, W_fc, beta_raw,
                                                    x_bf, wq_bf, wfc_bf, beta);

  gemm256<0, 1><<<256, 512, 0, stream>>>(x_bf, wq_bf, b_q, q_bf, M, H, H);

  scan_carry<<<NSEG * (NCH / 4) / 256, 256, 0, stream>>>((const uint2*)q_bf, carry, beta);
  scan_fuse<<<NSEG * (NCH / 4) / 256, 256, 0, stream>>>((const uint2*)q_bf,
                                                        (const float4*)carry, beta,
                                                        (uint2*)m_bf);

  gemm256<1, 0><<<256, 512, 0, stream>>>(m_bf, wfc_bf, b_fc, d_out, M, H, H);
}

// Round 2
// 237.657 us; speedup vs baseline: 1.0714x; 1.0104x over previous
//
#include <hip/hip_runtime.h>
#include <stdint.h>

typedef unsigned short u16;
typedef __bf16 bf16x8 __attribute__((ext_vector_type(8)));
typedef float f32x4 __attribute__((ext_vector_type(4)));

__device__ __forceinline__ u16 f2bf(float f) {
  union { float f; uint32_t u; } x; x.f = f;
  uint32_t u = x.u;
  u += 0x7fffu + ((u >> 16) & 1u);   // round-to-nearest-even
  return (u16)(u >> 16);
}
__device__ __forceinline__ float bf2f(uint32_t lo16) {
  union { uint32_t u; float f; } x; x.u = lo16 << 16; return x.f;
}

__device__ __forceinline__ void async_load16(const u16* g, u16* l) {
  __builtin_amdgcn_global_load_lds(
      (const __attribute__((address_space(1))) void*)g,
      (__attribute__((address_space(3))) void*)l,
      16, 0, 0);
}

// ---------------- prep_all: sigmoid(beta) + weight converts + x convert ----------------
__global__ __launch_bounds__(256) void prep_all(const float* __restrict__ x,
                                                const float* __restrict__ Wq,
                                                const float* __restrict__ Wfc,
                                                const float* __restrict__ braw,
                                                u16* __restrict__ xb,
                                                u16* __restrict__ wqb,
                                                u16* __restrict__ wfcb,
                                                float* __restrict__ beta) {
  int gid = blockIdx.x * 256 + threadIdx.x;
  if (gid < 1024) beta[gid] = 1.0f / (1.0f + expf(-braw[gid]));
  if (gid < 131072) {
    const int HH = 1024 * 1024;
    int i = gid * 16;
    const float* src = (i < HH) ? (Wq + i) : (Wfc + (i - HH));
    u16* dst = (i < HH) ? (wqb + i) : (wfcb + (i - HH));
#pragma unroll
    for (int c = 0; c < 4; c++) {
      float4 v = *(const float4*)(src + c * 4);
      ushort4 o = {f2bf(v.x), f2bf(v.y), f2bf(v.z), f2bf(v.w)};
      *(ushort4*)(dst + c * 4) = o;
    }
  }
  {
    int i = gid * 8;
    float4 a = *(const float4*)(x + i);
    float4 b = *(const float4*)(x + i + 4);
    ushort4 o0 = {f2bf(a.x), f2bf(a.y), f2bf(a.z), f2bf(a.w)};
    ushort4 o1 = {f2bf(b.x), f2bf(b.y), f2bf(b.z), f2bf(b.w)};
    *(ushort4*)(xb + i) = o0;
    *(ushort4*)(xb + i + 4) = o1;
  }
}

// ---------------- GEMM: C = A (MxK bf16) * B^T (NxK bf16) + bias ----------------
// 256x256 tile, BK=64, 8 waves (2Mx4N), per-wave 128x64, 8-phase schedule
// (4 phases per K-tile, 2 K-tiles per double-buffer period) -- the verified
// m201-family template expressed in plain HIP.
//
// LDS: 2 bufs x (A[256][64] + B[256][64]) bf16 = 128 KiB. Half-tile = 128 rows
// x 64 cols = 16 KB = 2 global_load_lds issues x 512 thr x 16 B.
//
// Per phase J of K-tile t (buf = t&1):
//   ds_read: A-frag rows {2J,2J+1} (4 x b128); phase 0 additionally all B
//            frags (8 x b128).
//   stage:   phase 0 -> A-halves 0+1 of tile t+1 (buf^1, 4 issues);
//            phase 1 -> B-half 0 of tile t+2 (buf, 2 issues);
//            phase 2 -> B-half 1 of tile t+2 (buf, 2 issues);
//            phase 3 -> none; counted s_waitcnt vmcnt(4) (never 0 in loop).
//   then: barrier; lgkmcnt(0); sched_barrier(0) [rule 18]; setprio(1);
//         16 MFMA; setprio(0); barrier.
//
// Race-freedom by barrier margin (not timing):
//  * B locations of buf are read ONLY at phase 0 (all 8 frags); their
//    overwrite (tile t+2's B) is ISSUED at phases 1/2, i.e. after phase 0's
//    end barrier, which is after every wave's phase-0 lgkmcnt(0) -> all reads
//    complete before any write is issued.
//  * A locations of buf^1 were last read at tile t-1 phase 3 (lgkmcnt(0)
//    before its end barrier); their overwrite (tile t+1's A) is issued at
//    tile t phase 0 -- one end-barrier later.
//  * Completeness: vmcnt(4) at phase 3 leaves exactly the 2 B-halves of t+2
//    in flight and guarantees A(t+1) (issued this tile, phase 0) and B(t+1)
//    (issued last tile, phases 1/2) have landed before any wave crosses into
//    tile t+1. Tail: t+2 >= NT -> vmcnt(0); t == NT-1 -> no wait.
//  * Side-effecting intrinsics (global_load_lds, s_barrier) keep program
//    order; ds_reads can't hoist past the "memory"-clobber waitcnt asm.
//
// LDS swizzle (T2, same family measured conflict-free in r0/r1): LDS[r][c]
// holds global chunk c ^ (r&7) (16B chunks); staged by pre-swizzling the
// global source chunk (linear LDS dest, m104 constraint); fragment reads
// XOR the chunk with lrow&7.
template <int RELU, int OUTBF>
__global__ __launch_bounds__(512, 2) void gemm256(const u16* __restrict__ A,
                                                  const u16* __restrict__ B,
                                                  const float* __restrict__ bias,
                                                  void* __restrict__ Cout,
                                                  int M, int N, int K) {
  __shared__ u16 lds[2][2][256 * 64];  // [buf][mat][row*64+col], 128 KiB

  const int tid  = threadIdx.x;
  const int lane = tid & 63;
  const int wid  = tid >> 6;          // 0..7
  const int wr   = (wid >> 2) * 128;  // wave row offset in tile
  const int wc   = (wid & 3) * 64;    // wave col offset in tile

  // XCD-aware map: grid 256 = 64 m-tiles x 4 n-tiles; xcd = bid&7 owns
  // m-tiles [8c, 8c+8) x all n -> blocks sharing an A-panel are concurrent
  // on one XCD's L2. 256 % 8 == 0 -> bijective.
  const int bid    = blockIdx.x;
  const int xcd    = bid & 7;
  const int idx    = bid >> 3;
  const int tile_m = ((xcd << 3) | (idx >> 2)) * 256;
  const int tile_n = (idx & 3) * 256;

  // staging map: one issue = 512 thr x 16B = 64 rows x 128B. Thread:
  // row-in-issue = tid>>3, dest chunk = tid&7, src chunk pre-swizzled.
  const int srow = tid >> 3;
  const int sch  = (tid & 7) ^ (srow & 7);
  const u16* gA = A + (size_t)(tile_m + srow) * K + sch * 8;
  const u16* gB = B + (size_t)(tile_n + srow) * K + sch * 8;

  // stage half h (0/1) of a matrix into buffer pointer bp, K-tile kt.
  // dest is linear: wave w covers rows h*128 + i*64 + [w*8, w*8+8).
#define STAGE_A(bp, h, kt)                                              \
  do {                                                                  \
    const u16* _s = gA + (size_t)(h) * 128 * K + (size_t)(kt) * 64;     \
    async_load16(_s,                 &(bp)[(h) * 8192 + wid * 512]);    \
    async_load16(_s + (size_t)64 * K,                                   \
                 &(bp)[(h) * 8192 + 4096 + wid * 512]);                 \
  } while (0)
#define STAGE_B(bp, h, kt)                                              \
  do {                                                                  \
    const u16* _s = gB + (size_t)(h) * 128 * K + (size_t)(kt) * 64;     \
    async_load16(_s,                 &(bp)[(h) * 8192 + wid * 512]);    \
    async_load16(_s + (size_t)64 * K,                                   \
                 &(bp)[(h) * 8192 + 4096 + wid * 512]);                 \
  } while (0)

  f32x4 acc[8][4];
#pragma unroll
  for (int i = 0; i < 8; i++)
#pragma unroll
    for (int j = 0; j < 4; j++) acc[i][j] = (f32x4){0.f, 0.f, 0.f, 0.f};

  const int lrow = lane & 15;
  const int kq   = lane >> 4;
  const int x0   = ((kq)     ^ (lrow & 7)) << 3;  // ksub 0 chunk offset (elems)
  const int x1   = ((kq + 4) ^ (lrow & 7)) << 3;  // ksub 1

  const int NT = K >> 6;  // K-tiles of 64 (K=1024 -> 16)

  // ---- prologue: tile 0 (all 4 halves) + tile 1's B halves; wait tile 0 ----
  {
    u16* b0A = &lds[0][0][0];
    u16* b0B = &lds[0][1][0];
    STAGE_B(b0B, 0, 0);
    STAGE_B(b0B, 1, 0);
    STAGE_A(b0A, 0, 0);
    STAGE_A(b0A, 1, 0);
    if (NT > 1) {
      u16* b1B = &lds[1][1][0];
      STAGE_B(b1B, 0, 1);
      STAGE_B(b1B, 1, 1);
      asm volatile("s_waitcnt vmcnt(4)" ::: "memory");
    } else {
      asm volatile("s_waitcnt vmcnt(0)" ::: "memory");
    }
  }
  __builtin_amdgcn_s_barrier();

  bf16x8 bfr[4][2];

  for (int t = 0; t < NT; ++t) {
    const int buf = t & 1;
    const u16* As = &lds[buf][0][0];
    const u16* Bs = &lds[buf][1][0];
    u16* nA = &lds[buf ^ 1][0][0];
    u16* cB = &lds[buf][1][0];  // tile t+2 shares this buffer's B region

    // ---------------- phase 0: B all + A rows 0,1 ; stage A(t+1) ----------------
#pragma unroll
    for (int n = 0; n < 4; n++) {
      bfr[n][0] = *(const bf16x8*)&Bs[(wc + n * 16 + lrow) * 64 + x0];
      bfr[n][1] = *(const bf16x8*)&Bs[(wc + n * 16 + lrow) * 64 + x1];
    }
    bf16x8 a0k0 = *(const bf16x8*)&As[(wr + 0 * 16 + lrow) * 64 + x0];
    bf16x8 a0k1 = *(const bf16x8*)&As[(wr + 0 * 16 + lrow) * 64 + x1];
    bf16x8 a1k0 = *(const bf16x8*)&As[(wr + 1 * 16 + lrow) * 64 + x0];
    bf16x8 a1k1 = *(const bf16x8*)&As[(wr + 1 * 16 + lrow) * 64 + x1];
    if (t + 1 < NT) { STAGE_A(nA, 0, t + 1); STAGE_A(nA, 1, t + 1); }
    __builtin_amdgcn_s_barrier();
    asm volatile("s_waitcnt lgkmcnt(0)" ::: "memory");
    __builtin_amdgcn_sched_barrier(0);
    __builtin_amdgcn_s_setprio(1);
#pragma unroll
    for (int n = 0; n < 4; n++) {
      acc[0][n] = __builtin_amdgcn_mfma_f32_16x16x32_bf16(a0k0, bfr[n][0], acc[0][n], 0, 0, 0);
      acc[1][n] = __builtin_amdgcn_mfma_f32_16x16x32_bf16(a1k0, bfr[n][0], acc[1][n], 0, 0, 0);
    }
#pragma unroll
    for (int n = 0; n < 4; n++) {
      acc[0][n] = __builtin_amdgcn_mfma_f32_16x16x32_bf16(a0k1, bfr[n][1], acc[0][n], 0, 0, 0);
      acc[1][n] = __builtin_amdgcn_mfma_f32_16x16x32_bf16(a1k1, bfr[n][1], acc[1][n], 0, 0, 0);
    }
    __builtin_amdgcn_s_setprio(0);
    __builtin_amdgcn_s_barrier();

    // ---------------- phase 1: A rows 2,3 ; stage B-half0(t+2) ----------------
    a0k0 = *(const bf16x8*)&As[(wr + 2 * 16 + lrow) * 64 + x0];
    a0k1 = *(const bf16x8*)&As[(wr + 2 * 16 + lrow) * 64 + x1];
    a1k0 = *(const bf16x8*)&As[(wr + 3 * 16 + lrow) * 64 + x0];
    a1k1 = *(const bf16x8*)&As[(wr + 3 * 16 + lrow) * 64 + x1];
    if (t + 2 < NT) STAGE_B(cB, 0, t + 2);
    __builtin_amdgcn_s_barrier();
    asm volatile("s_waitcnt lgkmcnt(0)" ::: "memory");
    __builtin_amdgcn_sched_barrier(0);
    __builtin_amdgcn_s_setprio(1);
#pragma unroll
    for (int n = 0; n < 4; n++) {
      acc[2][n] = __builtin_amdgcn_mfma_f32_16x16x32_bf16(a0k0, bfr[n][0], acc[2][n], 0, 0, 0);
      acc[3][n] = __builtin_amdgcn_mfma_f32_16x16x32_bf16(a1k0, bfr[n][0], acc[3][n], 0, 0, 0);
    }
#pragma unroll
    for (int n = 0; n < 4; n++) {
      acc[2][n] = __builtin_amdgcn_mfma_f32_16x16x32_bf16(a0k1, bfr[n][1], acc[2][n], 0, 0, 0);
      acc[3][n] = __builtin_amdgcn_mfma_f32_16x16x32_bf16(a1k1, bfr[n][1], acc[3][n], 0, 0, 0);
    }
    __builtin_amdgcn_s_setprio(0);
    __builtin_amdgcn_s_barrier();

    // ---------------- phase 2: A rows 4,5 ; stage B-half1(t+2) ----------------
    a0k0 = *(const bf16x8*)&As[(wr + 4 * 16 + lrow) * 64 + x0];
    a0k1 = *(const bf16x8*)&As[(wr + 4 * 16 + lrow) * 64 + x1];
    a1k0 = *(const bf16x8*)&As[(wr + 5 * 16 + lrow) * 64 + x0];
    a1k1 = *(const bf16x8*)&As[(wr + 5 * 16 + lrow) * 64 + x1];
    if (t + 2 < NT) STAGE_B(cB, 1, t + 2);
    __builtin_amdgcn_s_barrier();
    asm volatile("s_waitcnt lgkmcnt(0)" ::: "memory");
    __builtin_amdgcn_sched_barrier(0);
    __builtin_amdgcn_s_setprio(1);
#pragma unroll
    for (int n = 0; n < 4; n++) {
      acc[4][n] = __builtin_amdgcn_mfma_f32_16x16x32_bf16(a0k0, bfr[n][0], acc[4][n], 0, 0, 0);
      acc[5][n] = __builtin_amdgcn_mfma_f32_16x16x32_bf16(a1k0, bfr[n][0], acc[5][n], 0, 0, 0);
    }
#pragma unroll
    for (int n = 0; n < 4; n++) {
      acc[4][n] = __builtin_amdgcn_mfma_f32_16x16x32_bf16(a0k1, bfr[n][1], acc[4][n], 0, 0, 0);
      acc[5][n] = __builtin_amdgcn_mfma_f32_16x16x32_bf16(a1k1, bfr[n][1], acc[5][n], 0, 0, 0);
    }
    __builtin_amdgcn_s_setprio(0);
    __builtin_amdgcn_s_barrier();

    // ---------------- phase 3: A rows 6,7 ; counted vmcnt ----------------
    a0k0 = *(const bf16x8*)&As[(wr + 6 * 16 + lrow) * 64 + x0];
    a0k1 = *(const bf16x8*)&As[(wr + 6 * 16 + lrow) * 64 + x1];
    a1k0 = *(const bf16x8*)&As[(wr + 7 * 16 + lrow) * 64 + x0];
    a1k1 = *(const bf16x8*)&As[(wr + 7 * 16 + lrow) * 64 + x1];
    if (t < NT - 1) {
      if (t + 2 < NT) asm volatile("s_waitcnt vmcnt(4)" ::: "memory");
      else            asm volatile("s_waitcnt vmcnt(0)" ::: "memory");
    }
    __builtin_amdgcn_s_barrier();
    asm volatile("s_waitcnt lgkmcnt(0)" ::: "memory");
    __builtin_amdgcn_sched_barrier(0);
    __builtin_amdgcn_s_setprio(1);
#pragma unroll
    for (int n = 0; n < 4; n++) {
      acc[6][n] = __builtin_amdgcn_mfma_f32_16x16x32_bf16(a0k0, bfr[n][0], acc[6][n], 0, 0, 0);
      acc[7][n] = __builtin_amdgcn_mfma_f32_16x16x32_bf16(a1k0, bfr[n][0], acc[7][n], 0, 0, 0);
    }
#pragma unroll
    for (int n = 0; n < 4; n++) {
      acc[6][n] = __builtin_amdgcn_mfma_f32_16x16x32_bf16(a0k1, bfr[n][1], acc[6][n], 0, 0, 0);
      acc[7][n] = __builtin_amdgcn_mfma_f32_16x16x32_bf16(a1k1, bfr[n][1], acc[7][n], 0, 0, 0);
    }
    __builtin_amdgcn_s_setprio(0);
    if (t < NT - 1) __builtin_amdgcn_s_barrier();
  }
#undef STAGE_A
#undef STAGE_B

  // C/D layout: col = lane&15, row = (lane>>4)*4 + r  [measured m89/m91]
  const int crow = (lane >> 4) << 2;
  const int ccol = lane & 15;
#pragma unroll
  for (int i = 0; i < 8; i++) {
#pragma unroll
    for (int j = 0; j < 4; j++) {
      const int gm = tile_m + wr + i * 16 + crow;
      const int gn = tile_n + wc + j * 16 + ccol;
      const float bv = bias[gn];
#pragma unroll
      for (int r = 0; r < 4; r++) {
        float v = acc[i][j][r] + bv;
        if (RELU) v = fmaxf(v, 0.f);
        if (OUTBF) ((u16*)Cout)[(size_t)(gm + r) * N + gn] = f2bf(v);
        else       ((float*)Cout)[(size_t)(gm + r) * N + gn] = v;
      }
    }
  }
}

// ---------------- scan: m_t = beta*m_{t-1} + q_t over T=2048, channels = B*H = 8192 ----
// q is bf16 [T][8192]. 64 segments of 32 t-steps.
#define NCH 8192
#define SEG 32
#define NSEG 64

// pass1: per-segment carries (fp32 Horner over bf16 q; no double quantization).
__global__ __launch_bounds__(256) void scan_carry(const uint2* __restrict__ qb,
                                                  float* __restrict__ carry,
                                                  const float* __restrict__ beta_arr) {
  int tid = blockIdx.x * 256 + threadIdx.x;  // [0, 64*2048)
  int seg = tid >> 11;
  int cq  = tid & 2047;                      // channel quad
  int h0  = (cq * 4) & 1023;
  float b0 = beta_arr[h0], b1 = beta_arr[h0 + 1], b2 = beta_arr[h0 + 2], b3 = beta_arr[h0 + 3];
  const uint2* p = qb + (size_t)seg * SEG * 2048 + cq;
  float m0 = 0.f, m1 = 0.f, m2 = 0.f, m3 = 0.f;
#pragma unroll 8
  for (int t = 0; t < SEG; t++) {
    uint2 v = p[(size_t)t * 2048];
    m0 = fmaf(b0, m0, bf2f(v.x & 0xffffu));
    m1 = fmaf(b1, m1, bf2f(v.x >> 16));
    m2 = fmaf(b2, m2, bf2f(v.y & 0xffffu));
    m3 = fmaf(b3, m3, bf2f(v.y >> 16));
  }
  *(float4*)&carry[(size_t)seg * NCH + cq * 4] = make_float4(m0, m1, m2, m3);
}

// pass2 (fused fold + rescan): F = Horner-fold of the seg upstream carries with
// ratio beta^32 (2 MB buffer, L2-resident), then rescan 32 q steps from m=F and
// emit bf16 m. seg is uniform per block (8 blocks per segment).
__global__ __launch_bounds__(256) void scan_fuse(const uint2* __restrict__ qb,
                                                 const float4* __restrict__ carry4,
                                                 const float* __restrict__ beta_arr,
                                                 uint2* __restrict__ mb) {
  const int tid = blockIdx.x * 256 + threadIdx.x;  // [0, 64*2048)
  const int seg = tid >> 11;
  const int cq  = tid & 2047;
  const int h0  = (cq * 4) & 1023;
  const float b0 = beta_arr[h0], b1 = beta_arr[h0 + 1];
  const float b2 = beta_arr[h0 + 2], b3 = beta_arr[h0 + 3];
  float s0 = b0, s1 = b1, s2 = b2, s3 = b3;
#pragma unroll
  for (int i = 0; i < 5; i++) { s0 *= s0; s1 *= s1; s2 *= s2; s3 *= s3; }  // beta^32
  float m0 = 0.f, m1 = 0.f, m2 = 0.f, m3 = 0.f;
  const float4* cp = carry4 + cq;
  for (int s = 0; s < seg; s++) {  // uniform per block
    float4 c = cp[(size_t)s * 2048];
    m0 = fmaf(s0, m0, c.x); m1 = fmaf(s1, m1, c.y);
    m2 = fmaf(s2, m2, c.z); m3 = fmaf(s3, m3, c.w);
  }
  const uint2* p = qb + (size_t)seg * SEG * 2048 + cq;
  uint2* o = mb + (size_t)seg * SEG * 2048 + cq;
#pragma unroll 8
  for (int t = 0; t < SEG; t++) {
    uint2 v = p[(size_t)t * 2048];
    m0 = fmaf(b0, m0, bf2f(v.x & 0xffffu));
    m1 = fmaf(b1, m1, bf2f(v.x >> 16));
    m2 = fmaf(b2, m2, bf2f(v.y & 0xffffu));
    m3 = fmaf(b3, m3, bf2f(v.y >> 16));
    uint2 w;
    w.x = (uint32_t)f2bf(m0) | ((uint32_t)f2bf(m1) << 16);
    w.y = (uint32_t)f2bf(m2) | ((uint32_t)f2bf(m3) << 16);
    o[(size_t)t * 2048] = w;
  }
}

extern "C" void kernel_launch(void* const* d_in, const int* in_sizes, int n_in,
                              void* d_out, int out_size, void* d_ws, size_t ws_size,
                              hipStream_t stream) {
  const float* x        = (const float*)d_in[0];
  const float* W_q      = (const float*)d_in[1];
  const float* b_q      = (const float*)d_in[2];
  const float* beta_raw = (const float*)d_in[3];
  const float* W_fc     = (const float*)d_in[4];
  const float* b_fc     = (const float*)d_in[5];

  const int H = 1024;
  const int M = 2048 * 8;              // T*B = 16384 rows
  const size_t MH = (size_t)M * H;     // 16.7M elements

  char* ws = (char*)d_ws;
  u16* x_bf    = (u16*)ws;  ws += MH * 2;                   // 32 MB
  u16* q_bf    = (u16*)ws;  ws += MH * 2;                   // 32 MB
  u16* m_bf    = (u16*)ws;  ws += MH * 2;                   // 32 MB
  u16* wq_bf   = (u16*)ws;  ws += (size_t)H * H * 2;        // 2 MB
  u16* wfc_bf  = (u16*)ws;  ws += (size_t)H * H * 2;        // 2 MB
  float* beta  = (float*)ws; ws += 4096;
  float* carry = (float*)ws; ws += (size_t)NSEG * NCH * 4;  // 2 MB

  prep_all<<<(int)(MH / 8 / 256), 256, 0, stream>>>(x, W_q, W_fc, beta_raw,
                                                    x_bf, wq_bf, wfc_bf, beta);

  gemm256<0, 1><<<256, 512, 0, stream>>>(x_bf, wq_bf, b_q, q_bf, M, H, H);

  scan_carry<<<NSEG * (NCH / 4) / 256, 256, 0, stream>>>((const uint2*)q_bf, carry, beta);
  scan_fuse<<<NSEG * (NCH / 4) / 256, 256, 0, stream>>>((const uint2*)q_bf,
                                                        (const float4*)carry, beta,
                                                        (uint2*)m_bf);

  gemm256<1, 0><<<256, 512, 0, stream>>>(m_bf, wfc_bf, b_fc, d_out, M, H, H);
}